// Round 1
// baseline (2061.168 us; speedup 1.0000x reference)
//
#include <hip/hip_runtime.h>
#include <hip/hip_bf16.h>

#define NUM_TOK 8192
#define HID 1024
#define INT_DIM 4096
#define NEXP 8
#define NSLOT 16384  /* NUM_TOK * TOP_K */
#define BM 128
#define BK 32
#define LDA 40       /* padded LDS row stride (ushorts): 80B -> 2-way bank alias only */

typedef __bf16 bf16x8 __attribute__((ext_vector_type(8)));
typedef float f32x4 __attribute__((ext_vector_type(4)));

__device__ __forceinline__ unsigned short f2bf(float f) {
    unsigned int x = __builtin_bit_cast(unsigned int, f);
    x += 0x7fffu + ((x >> 16) & 1u);   // RNE
    return (unsigned short)(x >> 16);
}
__device__ __forceinline__ float bf2f(unsigned short u) {
    unsigned int x = ((unsigned int)u) << 16;
    return __builtin_bit_cast(float, x);
}

// ---------------- x -> bf16 ----------------
__global__ void k_convert_x(const float* __restrict__ x, unsigned short* __restrict__ xb) {
    size_t i = ((size_t)blockIdx.x * 256 + threadIdx.x) * 8;
    float4 a = *(const float4*)(x + i);
    float4 b = *(const float4*)(x + i + 4);
    union { unsigned short us[8]; uint4 v; } o;
    o.us[0] = f2bf(a.x); o.us[1] = f2bf(a.y); o.us[2] = f2bf(a.z); o.us[3] = f2bf(a.w);
    o.us[4] = f2bf(b.x); o.us[5] = f2bf(b.y); o.us[6] = f2bf(b.z); o.us[7] = f2bf(b.w);
    *(uint4*)(xb + i) = o.v;
}

// ---------------- router ----------------
__global__ __launch_bounds__(256) void k_router(
    const float* __restrict__ x, const float* __restrict__ gw,
    int* __restrict__ g_cnt, float* __restrict__ g_prob, float* __restrict__ g_z,
    int* __restrict__ btok, int4* __restrict__ tokInfo, float2* __restrict__ tokW)
{
    __shared__ float sGw[NEXP * HID];
    __shared__ float sProb[NEXP];
    __shared__ int   sCnt[NEXP];
    __shared__ float sZ;
    __shared__ int   sBase[NEXP];
    __shared__ int   rE0[64], rP0[64], rE1[64], rP1[64];
    __shared__ float rW0[64], rW1[64];

    int tid = threadIdx.x;
    for (int i = tid; i < NEXP * HID; i += 256) sGw[i] = gw[i];
    if (tid < NEXP) { sProb[tid] = 0.f; sCnt[tid] = 0; }
    if (tid == 0) sZ = 0.f;
    __syncthreads();

    int wave = tid >> 6, lane = tid & 63;
    for (int ti = 0; ti < 16; ++ti) {
        int lt = wave * 16 + ti;
        int t = blockIdx.x * 64 + lt;
        const float* xr = x + (size_t)t * HID;
        float acc[NEXP];
        #pragma unroll
        for (int e = 0; e < NEXP; ++e) acc[e] = 0.f;
        for (int k = lane; k < HID; k += 64) {
            float xv = xr[k];
            #pragma unroll
            for (int e = 0; e < NEXP; ++e) acc[e] += xv * sGw[e * HID + k];
        }
        #pragma unroll
        for (int e = 0; e < NEXP; ++e) {
            #pragma unroll
            for (int off = 32; off > 0; off >>= 1)
                acc[e] += __shfl_xor(acc[e], off);
        }
        if (lane == 0) {
            float m = acc[0];
            #pragma unroll
            for (int e = 1; e < NEXP; ++e) m = fmaxf(m, acc[e]);
            float s = 0.f;
            float p[NEXP];
            #pragma unroll
            for (int e = 0; e < NEXP; ++e) { p[e] = __expf(acc[e] - m); s += p[e]; }
            float inv = 1.f / s;
            // top-2 (first index wins ties, matching lax.top_k)
            float v1 = -1e30f, v2 = -1e30f; int i1 = -1, i2 = -1;
            #pragma unroll
            for (int e = 0; e < NEXP; ++e) {
                float v = acc[e];
                if (v > v1) { v2 = v1; i2 = i1; v1 = v; i1 = e; }
                else if (v > v2) { v2 = v; i2 = e; }
            }
            float e1v = __expf(v1 - m), e2v = __expf(v2 - m);
            float w0 = e1v / (e1v + e2v), w1 = e2v / (e1v + e2v);
            float lse = m + __logf(s);
            #pragma unroll
            for (int e = 0; e < NEXP; ++e) atomicAdd(&sProb[e], p[e] * inv);
            atomicAdd(&sZ, lse * lse);
            int p0 = atomicAdd(&sCnt[i1], 1);
            int p1 = atomicAdd(&sCnt[i2], 1);
            rE0[lt] = i1; rP0[lt] = p0; rE1[lt] = i2; rP1[lt] = p1;
            rW0[lt] = w0; rW1[lt] = w1;
        }
    }
    __syncthreads();
    if (tid < NEXP) {
        sBase[tid] = atomicAdd(&g_cnt[tid], sCnt[tid]);
        atomicAdd(&g_prob[tid], sProb[tid]);
    }
    if (tid == 64) atomicAdd(g_z, sZ);
    __syncthreads();
    if (tid < 64) {
        int t = blockIdx.x * 64 + tid;
        int e0 = rE0[tid], e1 = rE1[tid];
        int gp0 = sBase[e0] + rP0[tid];
        int gp1 = sBase[e1] + rP1[tid];
        btok[e0 * NUM_TOK + gp0] = t;
        btok[e1 * NUM_TOK + gp1] = t;
        tokInfo[t] = make_int4(e0, gp0, e1, gp1);
        tokW[t] = make_float2(rW0[tid], rW1[tid]);
    }
}

// ---------------- finalize: offsets + losses ----------------
__global__ void k_finalize(const int* __restrict__ g_cnt, const float* __restrict__ g_prob,
                           const float* __restrict__ g_z, int* __restrict__ offs,
                           float* __restrict__ out_tail)
{
    if (threadIdx.x == 0) {
        int o = 0; float lb = 0.f;
        for (int e = 0; e < NEXP; ++e) {
            offs[e] = o; o += g_cnt[e];
            lb += (float)g_cnt[e] * g_prob[e];
        }
        offs[NEXP] = o;
        out_tail[0] = (float)NEXP * lb / ((float)NUM_TOK * (float)NUM_TOK) * 0.01f;
        out_tail[1] = (g_z[0] / (float)NUM_TOK) * 0.001f;
    }
}

// ---------------- ffn1: gate+up GEMM + SiLU fuse -> h (bf16) ----------------
__global__ __launch_bounds__(256, 2) void k_ffn1(
    const unsigned short* __restrict__ xb, const float* __restrict__ wg,
    const float* __restrict__ wu, unsigned short* __restrict__ h,
    const int* __restrict__ btok, const int* __restrict__ cnt, const int* __restrict__ offs)
{
    int e = blockIdx.x >> 6;
    int mBase = (blockIdx.x & 63) * BM;
    int ne = cnt[e];
    if (mBase >= ne) return;
    int valid = ne - mBase; if (valid > BM) valid = BM;
    int nBase = blockIdx.y * 64;
    int slotBase = offs[e] + mBase;

    __shared__ alignas(16) unsigned short lA[BM * LDA];
    __shared__ alignas(16) unsigned short lBg[64 * LDA];
    __shared__ alignas(16) unsigned short lBu[64 * LDA];

    int tid = threadIdx.x;
    int r = tid >> 1;            // 0..127
    int ch = (tid & 1) * 16;     // col half: 0 or 16

    int aRow = (r < valid) ? r : 0;
    int tok = btok[e * NUM_TOK + mBase + aRow];
    const unsigned short* aSrc = xb + (size_t)tok * HID + ch;
    unsigned short* aDst = lA + r * LDA + ch;

    const float* bSrc;
    unsigned short* bDst;
    if (r < 64) {
        bSrc = wg + ((size_t)e * INT_DIM + nBase + r) * HID + ch;
        bDst = lBg + r * LDA + ch;
    } else {
        bSrc = wu + ((size_t)e * INT_DIM + nBase + (r - 64)) * HID + ch;
        bDst = lBu + (r - 64) * LDA + ch;
    }

    int wave = tid >> 6, lane = tid & 63;
    int mOff = (wave & 1) * 64;
    int nOff = (wave >> 1) * 32;
    int quad = lane >> 4, l16 = lane & 15;

    f32x4 accg[4][2] = {};
    f32x4 accu[4][2] = {};

    for (int k0 = 0; k0 < HID; k0 += BK) {
        uint4 a0 = *(const uint4*)(aSrc + k0);
        uint4 a1 = *(const uint4*)(aSrc + k0 + 8);
        float4 f0 = *(const float4*)(bSrc + k0);
        float4 f1 = *(const float4*)(bSrc + k0 + 4);
        float4 f2 = *(const float4*)(bSrc + k0 + 8);
        float4 f3 = *(const float4*)(bSrc + k0 + 12);
        union { unsigned short us[8]; uint4 v; } p0, p1;
        p0.us[0] = f2bf(f0.x); p0.us[1] = f2bf(f0.y); p0.us[2] = f2bf(f0.z); p0.us[3] = f2bf(f0.w);
        p0.us[4] = f2bf(f1.x); p0.us[5] = f2bf(f1.y); p0.us[6] = f2bf(f1.z); p0.us[7] = f2bf(f1.w);
        p1.us[0] = f2bf(f2.x); p1.us[1] = f2bf(f2.y); p1.us[2] = f2bf(f2.z); p1.us[3] = f2bf(f2.w);
        p1.us[4] = f2bf(f3.x); p1.us[5] = f2bf(f3.y); p1.us[6] = f2bf(f3.z); p1.us[7] = f2bf(f3.w);
        __syncthreads();
        *(uint4*)aDst = a0;
        *(uint4*)(aDst + 8) = a1;
        *(uint4*)bDst = p0.v;
        *(uint4*)(bDst + 8) = p1.v;
        __syncthreads();

        bf16x8 af[4];
        #pragma unroll
        for (int mi = 0; mi < 4; ++mi)
            af[mi] = *(const bf16x8*)(lA + (mOff + mi * 16 + l16) * LDA + quad * 8);
        bf16x8 bg0 = *(const bf16x8*)(lBg + (nOff + l16) * LDA + quad * 8);
        bf16x8 bg1 = *(const bf16x8*)(lBg + (nOff + 16 + l16) * LDA + quad * 8);
        bf16x8 bu0 = *(const bf16x8*)(lBu + (nOff + l16) * LDA + quad * 8);
        bf16x8 bu1 = *(const bf16x8*)(lBu + (nOff + 16 + l16) * LDA + quad * 8);
        #pragma unroll
        for (int mi = 0; mi < 4; ++mi) {
            accg[mi][0] = __builtin_amdgcn_mfma_f32_16x16x32_bf16(af[mi], bg0, accg[mi][0], 0, 0, 0);
            accg[mi][1] = __builtin_amdgcn_mfma_f32_16x16x32_bf16(af[mi], bg1, accg[mi][1], 0, 0, 0);
            accu[mi][0] = __builtin_amdgcn_mfma_f32_16x16x32_bf16(af[mi], bu0, accu[mi][0], 0, 0, 0);
            accu[mi][1] = __builtin_amdgcn_mfma_f32_16x16x32_bf16(af[mi], bu1, accu[mi][1], 0, 0, 0);
        }
    }

    #pragma unroll
    for (int mi = 0; mi < 4; ++mi) {
        #pragma unroll
        for (int rr = 0; rr < 4; ++rr) {
            int row = mOff + mi * 16 + quad * 4 + rr;
            if (row < valid) {
                size_t base = (size_t)(slotBase + row) * INT_DIM + nBase;
                #pragma unroll
                for (int nj = 0; nj < 2; ++nj) {
                    float g = accg[mi][nj][rr];
                    float u = accu[mi][nj][rr];
                    float hv = (g / (1.f + __expf(-g))) * u;
                    h[base + nOff + nj * 16 + l16] = f2bf(hv);
                }
            }
        }
    }
}

// ---------------- ffn2: h @ w_down^T -> y (fp32) ----------------
__global__ __launch_bounds__(256, 2) void k_ffn2(
    const unsigned short* __restrict__ h, const float* __restrict__ wd,
    float* __restrict__ y,
    const int* __restrict__ cnt, const int* __restrict__ offs)
{
    int e = blockIdx.x >> 6;
    int mBase = (blockIdx.x & 63) * BM;
    int ne = cnt[e];
    if (mBase >= ne) return;
    int valid = ne - mBase; if (valid > BM) valid = BM;
    int nBase = blockIdx.y * 64;
    int slotBase = offs[e] + mBase;

    __shared__ alignas(16) unsigned short lA[BM * LDA];
    __shared__ alignas(16) unsigned short lB[64 * LDA];

    int tid = threadIdx.x;
    int r = tid >> 1;
    int ch = (tid & 1) * 16;
    int aRow = (r < valid) ? r : 0;
    const unsigned short* aSrc = h + (size_t)(slotBase + aRow) * INT_DIM + ch;
    unsigned short* aDst = lA + r * LDA + ch;

    int rB = tid >> 2;           // 0..63
    int cB = (tid & 3) * 8;      // 0,8,16,24
    const float* bSrc = wd + ((size_t)e * HID + nBase + rB) * INT_DIM + cB;
    unsigned short* bDst = lB + rB * LDA + cB;

    int wave = tid >> 6, lane = tid & 63;
    int mOff = (wave & 1) * 64;
    int nOff = (wave >> 1) * 32;
    int quad = lane >> 4, l16 = lane & 15;

    f32x4 acc[4][2] = {};

    for (int k0 = 0; k0 < INT_DIM; k0 += BK) {
        uint4 a0 = *(const uint4*)(aSrc + k0);
        uint4 a1 = *(const uint4*)(aSrc + k0 + 8);
        float4 f0 = *(const float4*)(bSrc + k0);
        float4 f1 = *(const float4*)(bSrc + k0 + 4);
        union { unsigned short us[8]; uint4 v; } pk;
        pk.us[0] = f2bf(f0.x); pk.us[1] = f2bf(f0.y); pk.us[2] = f2bf(f0.z); pk.us[3] = f2bf(f0.w);
        pk.us[4] = f2bf(f1.x); pk.us[5] = f2bf(f1.y); pk.us[6] = f2bf(f1.z); pk.us[7] = f2bf(f1.w);
        __syncthreads();
        *(uint4*)aDst = a0;
        *(uint4*)(aDst + 8) = a1;
        *(uint4*)bDst = pk.v;
        __syncthreads();

        bf16x8 af[4];
        #pragma unroll
        for (int mi = 0; mi < 4; ++mi)
            af[mi] = *(const bf16x8*)(lA + (mOff + mi * 16 + l16) * LDA + quad * 8);
        bf16x8 b0 = *(const bf16x8*)(lB + (nOff + l16) * LDA + quad * 8);
        bf16x8 b1 = *(const bf16x8*)(lB + (nOff + 16 + l16) * LDA + quad * 8);
        #pragma unroll
        for (int mi = 0; mi < 4; ++mi) {
            acc[mi][0] = __builtin_amdgcn_mfma_f32_16x16x32_bf16(af[mi], b0, acc[mi][0], 0, 0, 0);
            acc[mi][1] = __builtin_amdgcn_mfma_f32_16x16x32_bf16(af[mi], b1, acc[mi][1], 0, 0, 0);
        }
    }

    #pragma unroll
    for (int mi = 0; mi < 4; ++mi) {
        #pragma unroll
        for (int rr = 0; rr < 4; ++rr) {
            int row = mOff + mi * 16 + quad * 4 + rr;
            if (row < valid) {
                size_t base = (size_t)(slotBase + row) * HID + nBase;
                #pragma unroll
                for (int nj = 0; nj < 2; ++nj)
                    y[base + nOff + nj * 16 + l16] = acc[mi][nj][rr];
            }
        }
    }
}

// ---------------- combine: out = w0*y0 + w1*y1 ----------------
__global__ void k_combine(const float* __restrict__ y,
                          const int4* __restrict__ tokInfo, const float2* __restrict__ tokW,
                          const int* __restrict__ offs, float* __restrict__ out)
{
    int t = blockIdx.x;
    int tid = threadIdx.x;
    int4 inf = tokInfo[t];
    float2 w = tokW[t];
    size_t s0 = (size_t)(offs[inf.x] + inf.y) * HID;
    size_t s1 = (size_t)(offs[inf.z] + inf.w) * HID;
    int c = tid * 4;
    float4 ya = *(const float4*)(y + s0 + c);
    float4 yb = *(const float4*)(y + s1 + c);
    float4 o;
    o.x = w.x * ya.x + w.y * yb.x;
    o.y = w.x * ya.y + w.y * yb.y;
    o.z = w.x * ya.z + w.y * yb.z;
    o.w = w.x * ya.w + w.y * yb.w;
    *(float4*)(out + (size_t)t * HID + c) = o;
}

extern "C" void kernel_launch(void* const* d_in, const int* in_sizes, int n_in,
                              void* d_out, int out_size, void* d_ws, size_t ws_size,
                              hipStream_t stream) {
    const float* x  = (const float*)d_in[0];
    const float* gw = (const float*)d_in[1];
    const float* wg = (const float*)d_in[2];
    const float* wu = (const float*)d_in[3];
    const float* wd = (const float*)d_in[4];
    float* out = (float*)d_out;

    char* p = (char*)d_ws;
    unsigned short* xb = (unsigned short*)p; p += (size_t)NUM_TOK * HID * 2;      // 16 MB
    unsigned short* h  = (unsigned short*)p; p += (size_t)NSLOT * INT_DIM * 2;    // 128 MB
    float* y           = (float*)p;          p += (size_t)NSLOT * HID * 4;        // 64 MB
    int* btok          = (int*)p;            p += (size_t)NEXP * NUM_TOK * 4;     // 256 KB
    int4* tokInfo      = (int4*)p;           p += (size_t)NUM_TOK * 16;           // 128 KB
    float2* tokW       = (float2*)p;         p += (size_t)NUM_TOK * 8;            // 64 KB
    int* cnt           = (int*)p;            p += 32;
    float* probSum     = (float*)p;          p += 32;
    float* zSum        = (float*)p;          p += 16;
    int* offs          = (int*)p;            p += 64;

    hipMemsetAsync(cnt, 0, 80, stream);  // zeros cnt[8] + probSum[8] + zSum
    k_convert_x<<<4096, 256, 0, stream>>>(x, xb);
    k_router<<<128, 256, 0, stream>>>(x, gw, cnt, probSum, zSum, btok, tokInfo, tokW);
    k_finalize<<<1, 64, 0, stream>>>(cnt, probSum, zSum, offs, out + (size_t)NUM_TOK * HID);
    k_ffn1<<<dim3(512, 64), 256, 0, stream>>>(xb, wg, wu, h, btok, cnt, offs);
    k_ffn2<<<dim3(512, 16), 256, 0, stream>>>(h, wd, y, cnt, offs);
    k_combine<<<8192, 256, 0, stream>>>(y, tokInfo, tokW, offs, out);
}

// Round 2
// 1348.604 us; speedup vs baseline: 1.5284x; 1.5284x over previous
//
#include <hip/hip_runtime.h>
#include <hip/hip_bf16.h>

#define NUM_TOK 8192
#define HID 1024
#define INT_DIM 4096
#define NEXP 8
#define NSLOT 16384  /* NUM_TOK * TOP_K */
#define BM 128
#define BK 64

typedef __bf16 bf16x8 __attribute__((ext_vector_type(8)));
typedef float f32x4 __attribute__((ext_vector_type(4)));

typedef const __attribute__((address_space(1))) unsigned int* gas_t;
typedef __attribute__((address_space(3))) unsigned int* las_t;

__device__ __forceinline__ void gl_lds16(const unsigned short* g, unsigned short* l) {
    __builtin_amdgcn_global_load_lds((gas_t)g, (las_t)l, 16, 0, 0);
}

__device__ __forceinline__ unsigned short f2bf(float f) {
    unsigned int x = __builtin_bit_cast(unsigned int, f);
    x += 0x7fffu + ((x >> 16) & 1u);   // RNE
    return (unsigned short)(x >> 16);
}

// ---------------- fp32 -> bf16 bulk convert (x and weights) ----------------
__global__ void k_cvt(const float* __restrict__ src, unsigned short* __restrict__ dst) {
    size_t i = ((size_t)blockIdx.x * 256 + threadIdx.x) * 8;
    float4 a = *(const float4*)(src + i);
    float4 b = *(const float4*)(src + i + 4);
    union { unsigned short us[8]; uint4 v; } o;
    o.us[0] = f2bf(a.x); o.us[1] = f2bf(a.y); o.us[2] = f2bf(a.z); o.us[3] = f2bf(a.w);
    o.us[4] = f2bf(b.x); o.us[5] = f2bf(b.y); o.us[6] = f2bf(b.z); o.us[7] = f2bf(b.w);
    *(uint4*)(dst + i) = o.v;
}

// ---------------- router ----------------
__global__ __launch_bounds__(256) void k_router(
    const float* __restrict__ x, const float* __restrict__ gw,
    int* __restrict__ g_cnt, float* __restrict__ g_prob, float* __restrict__ g_z,
    int* __restrict__ btok, float* __restrict__ bw)
{
    __shared__ float sGw[NEXP * HID];
    __shared__ float sProb[NEXP];
    __shared__ int   sCnt[NEXP];
    __shared__ float sZ;
    __shared__ int   sBase[NEXP];
    __shared__ int   rE0[64], rP0[64], rE1[64], rP1[64];
    __shared__ float rW0[64], rW1[64];

    int tid = threadIdx.x;
    for (int i = tid; i < NEXP * HID; i += 256) sGw[i] = gw[i];
    if (tid < NEXP) { sProb[tid] = 0.f; sCnt[tid] = 0; }
    if (tid == 0) sZ = 0.f;
    __syncthreads();

    int wave = tid >> 6, lane = tid & 63;
    for (int ti = 0; ti < 16; ++ti) {
        int lt = wave * 16 + ti;
        int t = blockIdx.x * 64 + lt;
        const float* xr = x + (size_t)t * HID;
        float acc[NEXP];
        #pragma unroll
        for (int e = 0; e < NEXP; ++e) acc[e] = 0.f;
        for (int k = lane; k < HID; k += 64) {
            float xv = xr[k];
            #pragma unroll
            for (int e = 0; e < NEXP; ++e) acc[e] += xv * sGw[e * HID + k];
        }
        #pragma unroll
        for (int e = 0; e < NEXP; ++e) {
            #pragma unroll
            for (int off = 32; off > 0; off >>= 1)
                acc[e] += __shfl_xor(acc[e], off);
        }
        if (lane == 0) {
            float m = acc[0];
            #pragma unroll
            for (int e = 1; e < NEXP; ++e) m = fmaxf(m, acc[e]);
            float s = 0.f;
            float p[NEXP];
            #pragma unroll
            for (int e = 0; e < NEXP; ++e) { p[e] = __expf(acc[e] - m); s += p[e]; }
            float inv = 1.f / s;
            float v1 = -1e30f, v2 = -1e30f; int i1 = -1, i2 = -1;
            #pragma unroll
            for (int e = 0; e < NEXP; ++e) {
                float v = acc[e];
                if (v > v1) { v2 = v1; i2 = i1; v1 = v; i1 = e; }
                else if (v > v2) { v2 = v; i2 = e; }
            }
            float e1v = __expf(v1 - m), e2v = __expf(v2 - m);
            float w0 = e1v / (e1v + e2v), w1 = e2v / (e1v + e2v);
            float lse = m + __logf(s);
            #pragma unroll
            for (int e = 0; e < NEXP; ++e) atomicAdd(&sProb[e], p[e] * inv);
            atomicAdd(&sZ, lse * lse);
            int p0 = atomicAdd(&sCnt[i1], 1);
            int p1 = atomicAdd(&sCnt[i2], 1);
            rE0[lt] = i1; rP0[lt] = p0; rE1[lt] = i2; rP1[lt] = p1;
            rW0[lt] = w0; rW1[lt] = w1;
        }
    }
    __syncthreads();
    if (tid < NEXP) {
        sBase[tid] = atomicAdd(&g_cnt[tid], sCnt[tid]);
        atomicAdd(&g_prob[tid], sProb[tid]);
    }
    if (tid == 64) atomicAdd(g_z, sZ);
    __syncthreads();
    if (tid < 64) {
        int t = blockIdx.x * 64 + tid;
        int e0 = rE0[tid], e1 = rE1[tid];
        int gp0 = sBase[e0] + rP0[tid];
        int gp1 = sBase[e1] + rP1[tid];
        btok[e0 * NUM_TOK + gp0] = t;
        btok[e1 * NUM_TOK + gp1] = t;
        bw[e0 * NUM_TOK + gp0] = rW0[tid];
        bw[e1 * NUM_TOK + gp1] = rW1[tid];
    }
}

// ---------------- finalize: offsets + losses ----------------
__global__ void k_finalize(const int* __restrict__ g_cnt, const float* __restrict__ g_prob,
                           const float* __restrict__ g_z, int* __restrict__ offs,
                           float* __restrict__ out_tail)
{
    if (threadIdx.x == 0) {
        int o = 0; float lb = 0.f;
        for (int e = 0; e < NEXP; ++e) {
            offs[e] = o; o += g_cnt[e];
            lb += (float)g_cnt[e] * g_prob[e];
        }
        offs[NEXP] = o;
        out_tail[0] = (float)NEXP * lb / ((float)NUM_TOK * (float)NUM_TOK) * 0.01f;
        out_tail[1] = (g_z[0] / (float)NUM_TOK) * 0.001f;
    }
}

// ---------------- ffn1: [gate|up] GEMM + SiLU -> h (bf16) ----------------
// Tile: M=128 tokens x N=64 gate cols + 64 up cols (128 B-rows), BK=64.
// LDS unpadded, XOR-8 16B-chunk swizzle applied on the GLOBAL source address
// (global_load_lds dest is wave-uniform + lane*16, so LDS side is fixed).
__global__ __launch_bounds__(256, 3) void k_ffn1(
    const unsigned short* __restrict__ xb, const unsigned short* __restrict__ wgb,
    const unsigned short* __restrict__ wub, unsigned short* __restrict__ h,
    const int* __restrict__ btok, const int* __restrict__ cnt, const int* __restrict__ offs)
{
    int e = blockIdx.x >> 6;
    int mBase = (blockIdx.x & 63) * BM;
    int ne = cnt[e];
    if (mBase >= ne) return;
    int valid = ne - mBase; if (valid > BM) valid = BM;
    int nBase = blockIdx.y * 64;
    int slotBase = offs[e] + mBase;

    __shared__ alignas(16) unsigned short lA[BM * BK];    // 16 KB
    __shared__ alignas(16) unsigned short lB[128 * BK];   // 16 KB

    int tid = threadIdx.x;
    int w = tid >> 6, lane = tid & 63;
    int lr = lane >> 3;              // 0..7: row within 8-row group
    int q  = (lane & 7) ^ lr;        // swizzled logical 16B-chunk

    // A staging: wave w stages rows [w*32, w*32+32), 4 instrs x 8 rows
    const unsigned short* aSrc[4];
    unsigned short* aDst[4];
    #pragma unroll
    for (int t = 0; t < 4; ++t) {
        int r = w * 32 + t * 8 + lr;
        int row = mBase + r; if (row > ne - 1) row = ne - 1;
        int tok = btok[e * NUM_TOK + row];
        aSrc[t] = xb + (size_t)tok * HID + q * 8;
        aDst[t] = lA + (w * 32 + t * 8) * BK;
    }
    // B staging: LDS row rb -> j=(rb>>5)*16+(rb&15), is_up=(rb>>4)&1
    const unsigned short* bSrc[4];
    unsigned short* bDst[4];
    #pragma unroll
    for (int t = 0; t < 4; ++t) {
        int j = w * 16 + (t & 1) * 8 + lr;
        const unsigned short* wsrc = (t >> 1) ? wub : wgb;
        bSrc[t] = wsrc + ((size_t)e * INT_DIM + nBase + j) * HID + q * 8;
        bDst[t] = lB + (w * 32 + t * 8) * BK;
    }

    int mOff = (w & 1) * 64, nOff = (w >> 1) * 64;
    int quad = lane >> 4, l16 = lane & 15;

    f32x4 acc[4][4] = {};

    for (int k0 = 0; k0 < HID; k0 += BK) {
        __syncthreads();
        #pragma unroll
        for (int t = 0; t < 4; ++t) gl_lds16(aSrc[t] + k0, aDst[t]);
        #pragma unroll
        for (int t = 0; t < 4; ++t) gl_lds16(bSrc[t] + k0, bDst[t]);
        __syncthreads();
        #pragma unroll
        for (int kk = 0; kk < 2; ++kk) {
            bf16x8 af[4], bfr[4];
            #pragma unroll
            for (int mi = 0; mi < 4; ++mi) {
                int r = mOff + mi * 16 + l16;
                af[mi] = *(const bf16x8*)(lA + r * BK + (((kk * 4 + quad) ^ (r & 7)) * 8));
            }
            #pragma unroll
            for (int ni = 0; ni < 4; ++ni) {
                int r = nOff + ni * 16 + l16;
                bfr[ni] = *(const bf16x8*)(lB + r * BK + (((kk * 4 + quad) ^ (r & 7)) * 8));
            }
            #pragma unroll
            for (int mi = 0; mi < 4; ++mi)
                #pragma unroll
                for (int ni = 0; ni < 4; ++ni)
                    acc[mi][ni] = __builtin_amdgcn_mfma_f32_16x16x32_bf16(af[mi], bfr[ni], acc[mi][ni], 0, 0, 0);
        }
    }

    // epilogue: ni even = gate, ni odd = up at same j = (nOff>>1) + (ni>>1)*16 + l16
    #pragma unroll
    for (int mi = 0; mi < 4; ++mi) {
        #pragma unroll
        for (int rr = 0; rr < 4; ++rr) {
            int row = mOff + mi * 16 + quad * 4 + rr;
            if (row < valid) {
                size_t base = (size_t)(slotBase + row) * INT_DIM + nBase;
                #pragma unroll
                for (int p = 0; p < 2; ++p) {
                    float g = acc[mi][2 * p][rr];
                    float u = acc[mi][2 * p + 1][rr];
                    float hv = (g / (1.f + __expf(-g))) * u;
                    h[base + (nOff >> 1) + p * 16 + l16] = f2bf(hv);
                }
            }
        }
    }
}

// ---------------- ffn2: h @ w_down^T, fused weighted combine via atomicAdd ----------------
__global__ __launch_bounds__(256, 3) void k_ffn2(
    const unsigned short* __restrict__ h, const unsigned short* __restrict__ wdb,
    float* __restrict__ out,
    const int* __restrict__ btok, const float* __restrict__ bw,
    const int* __restrict__ cnt, const int* __restrict__ offs)
{
    int e = blockIdx.x >> 6;
    int mBase = (blockIdx.x & 63) * BM;
    int ne = cnt[e];
    if (mBase >= ne) return;
    int valid = ne - mBase; if (valid > BM) valid = BM;
    int nBase = blockIdx.y * 128;
    int slotBase = offs[e] + mBase;

    __shared__ alignas(16) unsigned short lA[BM * BK];
    __shared__ alignas(16) unsigned short lB[128 * BK];

    int tid = threadIdx.x;
    int w = tid >> 6, lane = tid & 63;
    int lr = lane >> 3;
    int q  = (lane & 7) ^ lr;

    const unsigned short* aSrc[4];
    unsigned short* aDst[4];
    #pragma unroll
    for (int t = 0; t < 4; ++t) {
        int r = w * 32 + t * 8 + lr;
        int row = (r < valid) ? r : (valid - 1);
        aSrc[t] = h + (size_t)(slotBase + row) * INT_DIM + q * 8;
        aDst[t] = lA + (w * 32 + t * 8) * BK;
    }
    const unsigned short* bSrc[4];
    unsigned short* bDst[4];
    #pragma unroll
    for (int t = 0; t < 4; ++t) {
        int rb = w * 32 + t * 8 + lr;
        bSrc[t] = wdb + ((size_t)e * HID + nBase + rb) * INT_DIM + q * 8;
        bDst[t] = lB + (w * 32 + t * 8) * BK;
    }

    int mOff = (w & 1) * 64, nOff = (w >> 1) * 64;
    int quad = lane >> 4, l16 = lane & 15;

    f32x4 acc[4][4] = {};

    for (int k0 = 0; k0 < INT_DIM; k0 += BK) {
        __syncthreads();
        #pragma unroll
        for (int t = 0; t < 4; ++t) gl_lds16(aSrc[t] + k0, aDst[t]);
        #pragma unroll
        for (int t = 0; t < 4; ++t) gl_lds16(bSrc[t] + k0, bDst[t]);
        __syncthreads();
        #pragma unroll
        for (int kk = 0; kk < 2; ++kk) {
            bf16x8 af[4], bfr[4];
            #pragma unroll
            for (int mi = 0; mi < 4; ++mi) {
                int r = mOff + mi * 16 + l16;
                af[mi] = *(const bf16x8*)(lA + r * BK + (((kk * 4 + quad) ^ (r & 7)) * 8));
            }
            #pragma unroll
            for (int ni = 0; ni < 4; ++ni) {
                int r = nOff + ni * 16 + l16;
                bfr[ni] = *(const bf16x8*)(lB + r * BK + (((kk * 4 + quad) ^ (r & 7)) * 8));
            }
            #pragma unroll
            for (int mi = 0; mi < 4; ++mi)
                #pragma unroll
                for (int ni = 0; ni < 4; ++ni)
                    acc[mi][ni] = __builtin_amdgcn_mfma_f32_16x16x32_bf16(af[mi], bfr[ni], acc[mi][ni], 0, 0, 0);
        }
    }

    // epilogue: out[tok] += w_slot * y  (exactly 2 commutative fp32 adds per element)
    #pragma unroll
    for (int mi = 0; mi < 4; ++mi) {
        #pragma unroll
        for (int rr = 0; rr < 4; ++rr) {
            int row = mOff + mi * 16 + quad * 4 + rr;
            if (row < valid) {
                int tok = btok[e * NUM_TOK + mBase + row];
                float wgt = bw[e * NUM_TOK + mBase + row];
                float* obase = out + (size_t)tok * HID + nBase + nOff;
                #pragma unroll
                for (int ni = 0; ni < 4; ++ni)
                    atomicAdd(obase + ni * 16 + l16, wgt * acc[mi][ni][rr]);
            }
        }
    }
}

extern "C" void kernel_launch(void* const* d_in, const int* in_sizes, int n_in,
                              void* d_out, int out_size, void* d_ws, size_t ws_size,
                              hipStream_t stream) {
    const float* x  = (const float*)d_in[0];
    const float* gw = (const float*)d_in[1];
    const float* wg = (const float*)d_in[2];
    const float* wu = (const float*)d_in[3];
    const float* wd = (const float*)d_in[4];
    float* out = (float*)d_out;

    char* p = (char*)d_ws;
    unsigned short* xb  = (unsigned short*)p; p += (size_t)NUM_TOK * HID * 2;        // 16 MB
    unsigned short* h   = (unsigned short*)p; p += (size_t)NSLOT * INT_DIM * 2;      // 128 MB
    unsigned short* wgb = (unsigned short*)p; p += (size_t)NEXP * INT_DIM * HID * 2; // 64 MB
    unsigned short* wub = (unsigned short*)p; p += (size_t)NEXP * INT_DIM * HID * 2; // 64 MB
    unsigned short* wdb = (unsigned short*)p; p += (size_t)NEXP * HID * INT_DIM * 2; // 64 MB
    int* btok           = (int*)p;            p += (size_t)NEXP * NUM_TOK * 4;       // 256 KB
    float* bw           = (float*)p;          p += (size_t)NEXP * NUM_TOK * 4;       // 256 KB
    int* cnt            = (int*)p;            p += 32;
    float* probSum      = (float*)p;          p += 32;
    float* zSum         = (float*)p;          p += 16;
    int* offs           = (int*)p;            p += 64;

    hipMemsetAsync(cnt, 0, 80, stream);
    hipMemsetAsync(out, 0, (size_t)NUM_TOK * HID * sizeof(float), stream);

    k_cvt<<<4096, 256, 0, stream>>>(x, xb);                  // 8.4M elems
    k_cvt<<<16384, 256, 0, stream>>>(wg, wgb);               // 33.5M
    k_cvt<<<16384, 256, 0, stream>>>(wu, wub);
    k_cvt<<<16384, 256, 0, stream>>>(wd, wdb);
    k_router<<<128, 256, 0, stream>>>(x, gw, cnt, probSum, zSum, btok, bw);
    k_finalize<<<1, 64, 0, stream>>>(cnt, probSum, zSum, offs, out + (size_t)NUM_TOK * HID);
    k_ffn1<<<dim3(512, 64), 256, 0, stream>>>(xb, wgb, wub, h, btok, cnt, offs);
    k_ffn2<<<dim3(512, 8), 256, 0, stream>>>(h, wdb, out, btok, bw, cnt, offs);
}